// Round 3
// baseline (60.238 us; speedup 1.0000x reference)
//
#include <hip/hip_runtime.h>
#include <hip/hip_cooperative_groups.h>

namespace cg = cooperative_groups;

#define BROWS   8192
#define TPB     256
#define NTILE   (BROWS / TPB)     // 32
#define NBLOCKS (NTILE * NTILE)   // 1024  (= 4 blocks/CU, co-resident)

// loss = (1e-4 + sum_ij |A_i - D_i . logp_j|) / B^2   (C = 2)
// A_i = p.logp - q.log q ; D = p - q ; q = clip(onehot,1e-4,1)*class_w
__global__ __launch_bounds__(TPB) void fused_pair_loss_kernel(
    const float* __restrict__ s,        // [B,2]
    const float* __restrict__ cw,       // [2]
    const int*   __restrict__ t,        // [B]
    float* __restrict__ partials,       // [NBLOCKS] scratch (d_ws)
    float* __restrict__ out)            // [1]
{
    const int tid   = threadIdx.x;
    const int bid   = blockIdx.x;
    const int itile = bid & (NTILE - 1);
    const int jtile = bid >> 5;
    const float w0 = cw[0], w1 = cw[1];

    // ---- my i-row stats (registers) ----
    const int i = itile * TPB + tid;
    float2 si = *reinterpret_cast<const float2*>(s + 2 * i);
    float mi  = fmaxf(si.x, si.y);
    float ei0 = __expf(si.x - mi), ei1 = __expf(si.y - mi);
    float lsei = mi + __logf(ei0 + ei1);
    float li0 = si.x - lsei, li1 = si.y - lsei;
    float p0  = __expf(li0),  p1  = __expf(li1);
    const int ti = t[i];
    float q0 = (ti == 0 ? 1.0f : 1e-4f) * w0;
    float q1 = (ti == 1 ? 1.0f : 1e-4f) * w1;
    float A  = p0 * li0 + p1 * li1 - q0 * __logf(q0) - q1 * __logf(q1);
    float D0 = p0 - q0, D1 = p1 - q1;

    // ---- j-chunk logp into LDS, SoA + 16B aligned for b128 broadcasts ----
    __shared__ __align__(16) float ljx[TPB];
    __shared__ __align__(16) float ljy[TPB];
    const int j = jtile * TPB + tid;
    float2 sj = *reinterpret_cast<const float2*>(s + 2 * j);
    float mj  = fmaxf(sj.x, sj.y);
    float ej0 = __expf(sj.x - mj), ej1 = __expf(sj.y - mj);
    float lsej = mj + __logf(ej0 + ej1);
    ljx[tid] = sj.x - lsej;
    ljy[tid] = sj.y - lsej;
    __syncthreads();

    // ---- 256 pairs/thread; uniform b128 broadcasts; 4 ILP accumulators ----
    float a0 = 0.0f, a1 = 0.0f, a2 = 0.0f, a3 = 0.0f;
#pragma unroll
    for (int k = 0; k < TPB; k += 4) {
        float4 x = *reinterpret_cast<const float4*>(&ljx[k]);
        float4 y = *reinterpret_cast<const float4*>(&ljy[k]);
        a0 += fabsf(A - D0 * x.x - D1 * y.x);
        a1 += fabsf(A - D0 * x.y - D1 * y.y);
        a2 += fabsf(A - D0 * x.z - D1 * y.z);
        a3 += fabsf(A - D0 * x.w - D1 * y.w);
    }
    float acc = (a0 + a1) + (a2 + a3);

    // ---- block reduce: wave (64-lane) shuffles + LDS across 4 waves ----
    for (int off = 32; off > 0; off >>= 1)
        acc += __shfl_down(acc, off, 64);
    __shared__ float wsum[TPB / 64];
    if ((tid & 63) == 0) wsum[tid >> 6] = acc;
    __syncthreads();
    if (tid == 0)
        partials[bid] = wsum[0] + wsum[1] + wsum[2] + wsum[3];

    // ---- grid-wide barrier, then block 0 reduces the 1024 partials ----
    cg::this_grid().sync();

    if (bid == 0) {
        float4 v = reinterpret_cast<const float4*>(partials)[tid];
        float a = (v.x + v.y) + (v.z + v.w);
        for (int off = 32; off > 0; off >>= 1)
            a += __shfl_down(a, off, 64);
        __shared__ float wsum2[TPB / 64];
        if ((tid & 63) == 0) wsum2[tid >> 6] = a;
        __syncthreads();
        if (tid == 0) {
            float tot = wsum2[0] + wsum2[1] + wsum2[2] + wsum2[3];
            const float inv = 1.0f / ((float)BROWS * (float)BROWS);
            out[0] = (1e-4f + tot) * inv;
        }
    }
}

extern "C" void kernel_launch(void* const* d_in, const int* in_sizes, int n_in,
                              void* d_out, int out_size, void* d_ws, size_t ws_size,
                              hipStream_t stream) {
    const float* s  = (const float*)d_in[0];
    const float* cw = (const float*)d_in[1];
    const int*   t  = (const int*)d_in[2];
    float* out      = (float*)d_out;
    float* partials = (float*)d_ws;   // NBLOCKS floats, fully overwritten each call

    void* args[] = { (void*)&s, (void*)&cw, (void*)&t,
                     (void*)&partials, (void*)&out };
    hipLaunchCooperativeKernel((const void*)fused_pair_loss_kernel,
                               dim3(NBLOCKS), dim3(TPB), args, 0, stream);
}

// Round 4
// 15.310 us; speedup vs baseline: 3.9346x; 3.9346x over previous
//
#include <hip/hip_runtime.h>

#define BROWS   8192
#define TPB     256
#define ITILE   512
#define JTILE   512
#define GDIM    (BROWS / ITILE)    // 16
#define NBLOCKS (GDIM * GDIM)      // 256 partials

// loss = (1e-4 + sum_ij |A_i - D_i . logp_j|) / B^2   (C = 2)
// A_i = p.logp - q.log q ; D = p - q ; q = clip(onehot,1e-4,1)*class_w

__device__ __forceinline__ void row_stats(const float* __restrict__ s,
                                          const int* __restrict__ t,
                                          float w0, float w1, int i,
                                          float& A, float& D0, float& D1)
{
    float2 si = *reinterpret_cast<const float2*>(s + 2 * i);
    float m   = fmaxf(si.x, si.y);
    float e0  = __expf(si.x - m), e1 = __expf(si.y - m);
    float lse = m + __logf(e0 + e1);
    float l0  = si.x - lse, l1 = si.y - lse;
    float p0  = __expf(l0),  p1 = __expf(l1);
    const int ti = t[i];
    float q0 = (ti == 0 ? 1.0f : 1e-4f) * w0;
    float q1 = (ti == 1 ? 1.0f : 1e-4f) * w1;
    A  = p0 * l0 + p1 * l1 - q0 * __logf(q0) - q1 * __logf(q1);
    D0 = p0 - q0;
    D1 = p1 - q1;
}

__global__ __launch_bounds__(TPB) void pair_partial_kernel(
    const float* __restrict__ s,        // [B,2]
    const float* __restrict__ cw,       // [2]
    const int*   __restrict__ t,        // [B]
    float* __restrict__ partials)       // [NBLOCKS]
{
    const int tid = threadIdx.x;
    const int bx  = blockIdx.x;         // i-tile
    const int by  = blockIdx.y;         // j-tile
    const float w0 = cw[0], w1 = cw[1];

    // ---- stats for my 2 i-rows (registers) ----
    float A0, D00, D01, A1, D10, D11;
    row_stats(s, t, w0, w1, bx * ITILE + tid,       A0, D00, D01);
    row_stats(s, t, w0, w1, bx * ITILE + tid + TPB, A1, D10, D11);

    // ---- 512 j-row logp into LDS (2 per thread), SoA for b128 broadcast ----
    __shared__ __align__(16) float ljx[JTILE];
    __shared__ __align__(16) float ljy[JTILE];
#pragma unroll
    for (int r = 0; r < 2; ++r) {
        const int j = by * JTILE + tid + r * TPB;
        float2 sj = *reinterpret_cast<const float2*>(s + 2 * j);
        float m   = fmaxf(sj.x, sj.y);
        float e0  = __expf(sj.x - m), e1 = __expf(sj.y - m);
        float lse = m + __logf(e0 + e1);
        ljx[tid + r * TPB] = sj.x - lse;
        ljy[tid + r * TPB] = sj.y - lse;
    }
    __syncthreads();

    // ---- 1024 pairs/thread; each (x,y) reused for both i-rows ----
    float a0 = 0.0f, a1 = 0.0f, a2 = 0.0f, a3 = 0.0f;
#pragma unroll 4
    for (int k = 0; k < JTILE; k += 4) {
        float4 x = *reinterpret_cast<const float4*>(&ljx[k]);
        float4 y = *reinterpret_cast<const float4*>(&ljy[k]);
        a0 += fabsf(A0 - D00 * x.x - D01 * y.x);
        a1 += fabsf(A0 - D00 * x.y - D01 * y.y);
        a2 += fabsf(A0 - D00 * x.z - D01 * y.z);
        a3 += fabsf(A0 - D00 * x.w - D01 * y.w);
        a0 += fabsf(A1 - D10 * x.x - D11 * y.x);
        a1 += fabsf(A1 - D10 * x.y - D11 * y.y);
        a2 += fabsf(A1 - D10 * x.z - D11 * y.z);
        a3 += fabsf(A1 - D10 * x.w - D11 * y.w);
    }
    float acc = (a0 + a1) + (a2 + a3);

    // ---- block reduce: 64-lane wave shuffles + LDS across 4 waves ----
    for (int off = 32; off > 0; off >>= 1)
        acc += __shfl_down(acc, off, 64);
    __shared__ float wsum[TPB / 64];
    if ((tid & 63) == 0) wsum[tid >> 6] = acc;
    __syncthreads();
    if (tid == 0)
        partials[by * GDIM + bx] = wsum[0] + wsum[1] + wsum[2] + wsum[3];
}

// single-wave final reduce: 64 lanes x float4 = 256 partials
__global__ __launch_bounds__(64) void final_reduce_kernel(
    const float* __restrict__ partials, float* __restrict__ out)
{
    const int lane = threadIdx.x;
    float4 v = reinterpret_cast<const float4*>(partials)[lane];
    float a = (v.x + v.y) + (v.z + v.w);
    for (int off = 32; off > 0; off >>= 1)
        a += __shfl_down(a, off, 64);
    if (lane == 0) {
        const float inv = 1.0f / ((float)BROWS * (float)BROWS);
        out[0] = (1e-4f + a) * inv;
    }
}

extern "C" void kernel_launch(void* const* d_in, const int* in_sizes, int n_in,
                              void* d_out, int out_size, void* d_ws, size_t ws_size,
                              hipStream_t stream) {
    const float* s  = (const float*)d_in[0];
    const float* cw = (const float*)d_in[1];
    const int*   t  = (const int*)d_in[2];
    float* out      = (float*)d_out;
    float* partials = (float*)d_ws;   // NBLOCKS floats, fully overwritten each call

    dim3 grid(GDIM, GDIM);            // 16 x 16 blocks of 512x512 pairs
    pair_partial_kernel<<<grid, TPB, 0, stream>>>(s, cw, t, partials);
    final_reduce_kernel<<<1, 64, 0, stream>>>(partials, out);
}